// Round 8
// baseline (2466.118 us; speedup 1.0000x reference)
//
#include <hip/hip_runtime.h>
#include <hip/hip_bf16.h>

typedef float f32x4 __attribute__((ext_vector_type(4)));
typedef __bf16 bf16x8 __attribute__((ext_vector_type(8)));

#define DEV __device__ __forceinline__

namespace {

// Image padded 30x30 -> 32x32. Masks zero-padded -> every lane valid, pad
// pixels self-clean (relu(acc*0)=0).
//
// x lives in GLOBAL scratch (g_x, 80 KB/batch elem, L2-resident), not LDS:
// LDS = Yb + x1c/x2t + masks + xo = 77.9 KB -> 2 blocks/CU (was 158 KB ->
// 1 block/CU). 4 waves/SIMD from two INDEPENDENT blocks hide the barrier
// lock-step stalls that dominated v4 (MfmaUtil 7%, VALUBusy 24%, 70% idle).
constexpr int CSTR = 32 * 40 + 8;        // 1288: x1c/x2t channel stride
constexpr int E_Y  = 1024 * 16 + 32;     // Yb: 16 k-slots/pixel (+overread slack)
constexpr int E_C  = 8 * CSTR;           // 10304
constexpr int E_M  = 1024;
constexpr int SMEM_BYTES = (E_Y + 2 * E_C + 2 * E_M) * 2 + 400 * 4;  // 79744

DEV f32x4 mfma16(bf16x8 a, bf16x8 b, f32x4 c) {
    return __builtin_amdgcn_mfma_f32_16x16x32_bf16(a, b, c, 0, 0, 0);
}
DEV bf16x8 load8(const __bf16* p) { return *(const bf16x8*)p; }

// Yb bank swizzle: flip slot bit 3 by px bit 2 (lq stride) XOR px bit 7
// (lh stride 128 in OP2 writes — the bit the v4 formula missed).
DEV int yswz(int px) { return (((px >> 2) ^ (px >> 7)) & 1) << 3; }

} // namespace

// Per-batch x [1024 px][40 ch] bf16. +64 slack: zero-weighted k-overreads
// (ch 32..39 reads at lh>0 run past the row). Stale channels 3..39 on
// iter 0 are multiplied by zeroed weight lanes -> exact 0, deterministic.
__device__ __bf16 g_x[(size_t)2048 * 40960 + 64];

__global__ __attribute__((amdgpu_flat_work_group_size(512, 512)))
void ppgn_fused_v5(
    const float* __restrict__ X2g, const float* __restrict__ Mg,
    const float* __restrict__ w11, const float* __restrict__ w12,
    const float* __restrict__ w13, const float* __restrict__ wAg,
    const float* __restrict__ wBg, const float* __restrict__ wCg,
    const float* __restrict__ h1w, const float* __restrict__ h1b,
    float* __restrict__ out)
{
    extern __shared__ char smem[];
    __bf16* Yb  = (__bf16*)smem;          // [1024][16] Y k-slots, swizzled
    __bf16* x1c = Yb + E_Y;               // [8][32x40+8] x1 chunk [c][i][k=j]
    __bf16* x2t = x1c + E_C;              // [8][32x40+8] x2^T chunk [c][j][k=i]
    __bf16* MsL = x2t + E_C;              // [1024] M0+M1 (0 in pad)
    __bf16* M0L = MsL + E_M;              // [1024] M0
    float*  xo  = (float*)(M0L + E_M);    // [5][2][40] feature sums

    const int tid  = threadIdx.x;
    const int wv   = tid >> 6;
    const int lane = tid & 63;
    const int lq   = lane & 15;
    const int lh   = lane >> 4;
    const int b    = blockIdx.x;
    __bf16* gx = g_x + (size_t)b * 40960;

    // ---- zero LDS (xo needs 0; slack must be finite) ----
    {
        unsigned int* p = (unsigned int*)smem;
        for (int i = tid; i < SMEM_BYTES / 4; i += 512) p[i] = 0u;
    }

    // ---- stage x ch0..2 (global) and masks (LDS), zero-padded ----
    {
        const float* xb = X2g + b * 2700;
        for (int idx = tid; idx < 3072; idx += 512) {
            const int c = idx >> 10, px = idx & 1023;
            const int i = px >> 5, j = px & 31;
            const bool v = (i < 30) & (j < 30);
            gx[px * 40 + c] = v ? (__bf16)xb[c * 900 + i * 30 + j] : (__bf16)0.f;
        }
        const float* mb = Mg + b * 1800;
        for (int px = tid; px < 1024; px += 512) {
            const int i = px >> 5, j = px & 31;
            const bool v = (i < 30) & (j < 30);
            const float m0 = v ? mb[i * 30 + j] : 0.f;
            const float m1 = v ? mb[900 + i * 30 + j] : 0.f;
            MsL[px] = (__bf16)(m0 + m1);
            M0L[px] = (__bf16)m0;
        }
    }
    __syncthreads();

    f32x4 acc[8][3];

    for (int itb = 0; itb < 5; ++itb) {
        const float *wa, *wb, *wc;
        int kAB, sAB, kX, sC;
        if (itb == 0) { wa = w11; wb = w12; kAB = 3;  sAB = 3;  wc = w13; kX = 3;  sC = 43; }
        else {
            wa = wAg + (itb - 1) * 1600; wb = wBg + (itb - 1) * 1600; kAB = 40; sAB = 40;
            wc = wCg + (itb - 1) * 3200; kX = 40; sC = 80;
        }
        const bool generic = (itb == 0);

        #pragma unroll
        for (int i = 0; i < 8; ++i)
            #pragma unroll
            for (int m = 0; m < 3; ++m) acc[i][m] = f32x4{0.f, 0.f, 0.f, 0.f};

        // Op1: conv -> x1 (weight rows 0..7) / x2 (rows 8..15), one 8-ch chunk.
        // B-operand (x) read from GLOBAL; scatter into LDS x1c/x2t.
        auto OP1 = [&](int chunk) {
            const float* rowp = ((lq < 8) ? wa : wb) + (chunk * 8 + (lq & 7)) * sAB;
            bf16x8 af0, af1;
            if (!generic) {
                #pragma unroll
                for (int e = 0; e < 8; ++e) af0[e] = (__bf16)rowp[8 * lh + e];
                #pragma unroll
                for (int e = 0; e < 8; ++e) {        // k=32..39: only lh==0
                    const float v = rowp[(lh == 0) ? (32 + e) : e];
                    af1[e] = (lh == 0) ? (__bf16)v : (__bf16)0.f;
                }
            } else {
                #pragma unroll
                for (int e = 0; e < 8; ++e) {
                    const int k = 8 * lh + e;
                    const float v = rowp[(k < kAB) ? k : 0];
                    af0[e] = (k < kAB) ? (__bf16)v : (__bf16)0.f;
                }
            }
            #pragma unroll
            for (int it = 0; it < 8; ++it) {
                const int nt = 8 * wv + it;
                const int px = nt * 16 + lq;
                const __bf16* bp = gx + px * 40 + 8 * lh;
                f32x4 a4 = f32x4{0.f, 0.f, 0.f, 0.f};
                a4 = mfma16(af0, load8(bp), a4);
                if (!generic) a4 = mfma16(af1, load8(bp + 32), a4);
                const float ms = (float)MsL[px];
                const int ib = (nt >> 1) * 40;            // i*40 (wave-uniform)
                const int jj = ((nt & 1) << 4) + lq;      // j
                #pragma unroll
                for (int r = 0; r < 4; ++r) {
                    const int o = 4 * lh + r;
                    const __bf16 hv = (__bf16)fmaxf(a4[r] * ms, 0.f);
                    if (lh < 2) x1c[o * CSTR + ib + jj] = hv;          // [c][i][j]
                    else        x2t[(o - 8) * CSTR + jj * 40 + (nt >> 1)] = hv; // [c][j][i]
                }
            }
        };

        // Op2: per-channel (c = chunk*8+wv) 32x32x32 spatial matmul -> Yb slot.
        auto OP2 = [&](int chunk) {
            const __bf16* ab = x1c + wv * CSTR;
            const __bf16* bb = x2t + wv * CSTR;
            const int slot = 8 * (chunk & 1) + wv;
            #pragma unroll
            for (int m = 0; m < 2; ++m) {
                const bf16x8 aAm = load8(ab + (m * 16 + lq) * 40 + 8 * lh);
                #pragma unroll
                for (int n = 0; n < 2; ++n) {
                    const bf16x8 bBn = load8(bb + (n * 16 + lq) * 40 + 8 * lh);
                    f32x4 ay = f32x4{0.f, 0.f, 0.f, 0.f};
                    ay = mfma16(aAm, bBn, ay);
                    #pragma unroll
                    for (int r = 0; r < 4; ++r) {
                        const int px = (m * 16 + 4 * lh + r) * 32 + n * 16 + lq;
                        Yb[px * 16 + (slot ^ yswz(px))] = (__bf16)(ay[r] * (float)MsL[px]);
                    }
                }
            }
        };

        // Op3 partial: acc += wc[:, cp*16..+16) @ Y(16 slots).
        // (k-lanes >=16 read past the 16-slot row into slack/next row: weight
        // is zeroed there, so the contribution is exactly 0.)
        auto OP3 = [&](int cp) {
            bf16x8 yf[3];
            #pragma unroll
            for (int m = 0; m < 3; ++m) {
                const int o = m * 16 + lq;
                #pragma unroll
                for (int e = 0; e < 8; ++e) {
                    const int kl = 8 * lh + e, kg = cp * 16 + kl;
                    const bool ok = (o < 40) & (kl < 16) & (kg < 40);
                    const float v = wc[ok ? o * sC + kg : 0];
                    yf[m][e] = ok ? (__bf16)v : (__bf16)0.f;
                }
            }
            #pragma unroll
            for (int it = 0; it < 8; ++it) {
                const int px = (8 * wv + it) * 16 + lq;
                const bf16x8 bf = load8(Yb + px * 16 + (8 * lh ^ yswz(px)));
                #pragma unroll
                for (int m = 0; m < 3; ++m) acc[it][m] = mfma16(yf[m], bf, acc[it][m]);
            }
        };

        // Op3 x-part: acc += wc[:, 40+koff..] @ x (x from GLOBAL).
        auto XP = [&](int koff) {
            bf16x8 xf[3];
            #pragma unroll
            for (int m = 0; m < 3; ++m) {
                const int o = m * 16 + lq;
                #pragma unroll
                for (int e = 0; e < 8; ++e) {
                    const int k = koff + 8 * lh + e;
                    const bool ok = (o < 40) & (k < kX);
                    const float v = wc[ok ? o * sC + 40 + k : 0];
                    xf[m][e] = ok ? (__bf16)v : (__bf16)0.f;
                }
            }
            #pragma unroll
            for (int it = 0; it < 8; ++it) {
                const bf16x8 b0 = load8(gx + ((8 * wv + it) * 16 + lq) * 40 + koff + 8 * lh);
                #pragma unroll
                for (int m = 0; m < 3; ++m) acc[it][m] = mfma16(xf[m], b0, acc[it][m]);
            }
        };

        // 5 chunks. sched_barrier(0) separates OP3/XP register lifetimes from
        // neighbors (keeps peak pressure under the 128-VGPR cap: acc 96 +
        // one phase's transients <= ~120). No OP3/OP1 merge (v4's merge put
        // both transient sets live at once -> spill).
        OP1(0);                                   __syncthreads();
        OP2(0);                                   __syncthreads();
        OP1(1);                                   __syncthreads();
        OP2(1);                                   __syncthreads();
        OP3(0); __builtin_amdgcn_sched_barrier(0); OP1(2); __syncthreads();
        OP2(2);                                   __syncthreads();
        OP1(3);                                   __syncthreads();
        OP2(3);                                   __syncthreads();
        OP3(1); __builtin_amdgcn_sched_barrier(0); OP1(4); __syncthreads();
        OP2(4);                                   __syncthreads();
        OP3(2); __builtin_amdgcn_sched_barrier(0);
        XP(0);  __builtin_amdgcn_sched_barrier(0);
        if (kX > 32) XP(32);
        __syncthreads();                          // all x reads done

        // epilogue: xn = relu(acc*Ms) -> gx (packed 4ch/8B store); feature
        // sums from fp32 pre-rounding values.
        #pragma unroll
        for (int m = 0; m < 3; ++m) {
            float sA[4] = {0.f, 0.f, 0.f, 0.f};
            float sB[4] = {0.f, 0.f, 0.f, 0.f};
            const int o0 = m * 16 + 4 * lh;
            #pragma unroll
            for (int it = 0; it < 8; ++it) {
                const int px = (8 * wv + it) * 16 + lq;
                const float ms  = (float)MsL[px];
                const float m0v = (float)M0L[px];
                const float m1v = ms - m0v;
                union { __bf16 h[4]; uint2 u2; } pk;
                #pragma unroll
                for (int r = 0; r < 4; ++r) {
                    const float v = fmaxf(acc[it][m][r] * ms, 0.f);
                    pk.h[r] = (__bf16)v;
                    sA[r] += v * m0v;
                    sB[r] += v * m1v;
                }
                if (o0 < 40)   // m==2 valid only for lh<2 (wave-uniform-ish)
                    *reinterpret_cast<uint2*>(gx + px * 40 + o0) = pk.u2;
            }
            #pragma unroll
            for (int r = 0; r < 4; ++r) {
                float a = sA[r], b2 = sB[r];
                #pragma unroll
                for (int d = 1; d < 16; d <<= 1) {
                    a  += __shfl_xor(a, d, 64);
                    b2 += __shfl_xor(b2, d, 64);
                }
                const int o = o0 + r;
                if (lq == 0 && o < 40) {
                    atomicAdd(&xo[itb * 80 + o], a);
                    atomicAdd(&xo[itb * 80 + 40 + o], b2);
                }
            }
            __builtin_amdgcn_sched_barrier(0);
        }
        __syncthreads();
    }

    // ---- head: out = relu(feat @ h1w^T + h1b) ----
    {
        const int hh = wv * 4 + lh;   // 0..31
        float s = 0.f;
        #pragma unroll
        for (int k2 = 0; k2 < 25; ++k2) {
            const int f = lq + 16 * k2;
            s += xo[f] * h1w[hh * 400 + f];
        }
        #pragma unroll
        for (int d = 1; d < 16; d <<= 1) s += __shfl_xor(s, d, 64);
        if (lq == 0) out[b * 32 + hh] = fmaxf(s + h1b[hh], 0.f);
    }
}

extern "C" void kernel_launch(void* const* d_in, const int* in_sizes, int n_in,
                              void* d_out, int out_size, void* d_ws, size_t ws_size,
                              hipStream_t stream) {
    (void)in_sizes; (void)n_in; (void)d_ws; (void)ws_size; (void)out_size;
    const float* X2  = (const float*)d_in[0];
    const float* M   = (const float*)d_in[1];
    const float* w11 = (const float*)d_in[2];
    const float* w12 = (const float*)d_in[3];
    const float* w13 = (const float*)d_in[4];
    const float* wA  = (const float*)d_in[5];
    const float* wB  = (const float*)d_in[6];
    const float* wC  = (const float*)d_in[7];
    const float* h1w = (const float*)d_in[8];
    const float* h1b = (const float*)d_in[9];
    float* out = (float*)d_out;

    (void)hipFuncSetAttribute(reinterpret_cast<const void*>(ppgn_fused_v5),
                              hipFuncAttributeMaxDynamicSharedMemorySize, SMEM_BYTES);
    ppgn_fused_v5<<<2048, 512, SMEM_BYTES, stream>>>(X2, M, w11, w12, w13,
                                                     wA, wB, wC, h1w, h1b, out);
}